// Round 1
// baseline (1493.724 us; speedup 1.0000x reference)
//
#include <hip/hip_runtime.h>
#include <hip/hip_bf16.h>

#define N_NODES 50000
#define N_EDGES 800000
#define N_GRAPHS 64
#define D 320

// ---------------- degree / dinv ----------------
__global__ void k_deg(const int* __restrict__ dst, int* __restrict__ degi) {
    int e = blockIdx.x * blockDim.x + threadIdx.x;
    if (e < N_EDGES) atomicAdd(&degi[dst[e]], 1);
}

__global__ void k_dinv(const int* __restrict__ degi, float* __restrict__ dinv) {
    int n = blockIdx.x * blockDim.x + threadIdx.x;
    if (n < N_NODES) dinv[n] = rsqrtf((float)(degi[n] + 1)); // +1 self loop
}

// ---------------- exclusive scan (single block, 1024 thr) ----------------
__global__ void k_scan(const int* __restrict__ counts, int* __restrict__ offs) {
    __shared__ int tmp[1024];
    int t = threadIdx.x;
    int carry = 0;
    if (t == 0) offs[0] = 0;
    for (int base = 0; base < N_NODES; base += 1024) {
        int v = (base + t < N_NODES) ? counts[base + t] : 0;
        tmp[t] = v;
        __syncthreads();
        #pragma unroll
        for (int off = 1; off < 1024; off <<= 1) {
            int xv = (t >= off) ? tmp[t - off] : 0;
            __syncthreads();
            tmp[t] += xv;
            __syncthreads();
        }
        if (base + t < N_NODES) offs[base + t + 1] = carry + tmp[t];
        carry += tmp[1023];
        __syncthreads();
    }
}

// ---------------- CSR fill (bucket by dst, store src) ----------------
__global__ void k_fill(const int* __restrict__ src, const int* __restrict__ dst,
                       const int* __restrict__ offs, int* __restrict__ cursor,
                       int* __restrict__ csr) {
    int e = blockIdx.x * blockDim.x + threadIdx.x;
    if (e < N_EDGES) {
        int d = dst[e];
        int p = atomicAdd(&cursor[d], 1);
        csr[offs[d] + p] = src[e];
    }
}

// ---------------- fp32 tiled GEMM: P[m,n] = dinv[m] * sum_k A[m,k] W[k,n] ----------------
#define BM 64
#define BN 64
#define BK 16
__global__ __launch_bounds__(256) void k_gemm(const float* __restrict__ A,
                                              const float* __restrict__ W,
                                              const float* __restrict__ dinv,
                                              float* __restrict__ P) {
    __shared__ float As[BK][BM];
    __shared__ float Bs[BK][BN];
    int t  = threadIdx.x;
    int m0 = blockIdx.x * BM;
    int n0 = blockIdx.y * BN;
    int ty = t >> 4;   // 0..15
    int tx = t & 15;   // 0..15
    float acc[4][4] = {};
    int la_row = t >> 2;  // 0..63
    int la_k4  = t & 3;   // 0..3  (float4 within k-16)
    int lb_k   = t >> 4;  // 0..15
    int lb_c4  = t & 15;  // 0..15 (float4 within n-64)

    for (int k0 = 0; k0 < D; k0 += BK) {
        float4 av = make_float4(0.f, 0.f, 0.f, 0.f);
        int ar = m0 + la_row;
        if (ar < N_NODES) av = *(const float4*)&A[(long)ar * D + k0 + la_k4 * 4];
        As[la_k4 * 4 + 0][la_row] = av.x;
        As[la_k4 * 4 + 1][la_row] = av.y;
        As[la_k4 * 4 + 2][la_row] = av.z;
        As[la_k4 * 4 + 3][la_row] = av.w;
        float4 bv = *(const float4*)&W[(long)(k0 + lb_k) * D + n0 + lb_c4 * 4];
        *(float4*)&Bs[lb_k][lb_c4 * 4] = bv;
        __syncthreads();
        #pragma unroll
        for (int kk = 0; kk < BK; ++kk) {
            float4 a  = *(const float4*)&As[kk][ty * 4];
            float4 bq = *(const float4*)&Bs[kk][tx * 4];
            acc[0][0] = fmaf(a.x, bq.x, acc[0][0]);
            acc[0][1] = fmaf(a.x, bq.y, acc[0][1]);
            acc[0][2] = fmaf(a.x, bq.z, acc[0][2]);
            acc[0][3] = fmaf(a.x, bq.w, acc[0][3]);
            acc[1][0] = fmaf(a.y, bq.x, acc[1][0]);
            acc[1][1] = fmaf(a.y, bq.y, acc[1][1]);
            acc[1][2] = fmaf(a.y, bq.z, acc[1][2]);
            acc[1][3] = fmaf(a.y, bq.w, acc[1][3]);
            acc[2][0] = fmaf(a.z, bq.x, acc[2][0]);
            acc[2][1] = fmaf(a.z, bq.y, acc[2][1]);
            acc[2][2] = fmaf(a.z, bq.z, acc[2][2]);
            acc[2][3] = fmaf(a.z, bq.w, acc[2][3]);
            acc[3][0] = fmaf(a.w, bq.x, acc[3][0]);
            acc[3][1] = fmaf(a.w, bq.y, acc[3][1]);
            acc[3][2] = fmaf(a.w, bq.z, acc[3][2]);
            acc[3][3] = fmaf(a.w, bq.w, acc[3][3]);
        }
        __syncthreads();
    }
    #pragma unroll
    for (int i = 0; i < 4; ++i) {
        int row = m0 + ty * 4 + i;
        if (row < N_NODES) {
            float dv = dinv[row];
            float4 r;
            r.x = acc[i][0] * dv;
            r.y = acc[i][1] * dv;
            r.z = acc[i][2] * dv;
            r.w = acc[i][3] * dv;
            *(float4*)&P[(long)row * D + n0 + tx * 4] = r;
        }
    }
}

// ---------------- aggregation: H[n] = relu(dinv[n]*(P[n] + sum_{src->n} P[src]) + b) ----------------
__global__ void k_agg(const float* __restrict__ P, const int* __restrict__ offs,
                      const int* __restrict__ csr, const float* __restrict__ dinv,
                      const float* __restrict__ bias, float* __restrict__ H) {
    int n = blockIdx.x;
    int d = threadIdx.x;  // 320
    float acc = P[(long)n * D + d];  // self loop (dinv[n]*P'[n] handled by outer dinv)
    int i0 = offs[n], i1 = offs[n + 1];
    for (int i = i0; i < i1; ++i) {
        int s = csr[i];
        acc += P[(long)s * D + d];
    }
    H[(long)n * D + d] = fmaxf(fmaf(dinv[n], acc, bias[d]), 0.0f);
}

// ---------------- global max pool over sorted batch ----------------
__global__ void k_pool(const float* __restrict__ H, const int* __restrict__ batch,
                       float* __restrict__ G) {
    __shared__ int range[2];
    int b = blockIdx.x;   // 64
    int d = threadIdx.x;  // 320
    if (d < 2) {
        int target = b + d;  // first index with batch[] >= target
        int lo = 0, hi = N_NODES;
        while (lo < hi) {
            int mid = (lo + hi) >> 1;
            if (batch[mid] < target) lo = mid + 1; else hi = mid;
        }
        range[d] = lo;
    }
    __syncthreads();
    int s = range[0], e = range[1];
    float m = -INFINITY;
    for (int n = s; n < e; ++n) m = fmaxf(m, H[(long)n * D + d]);
    G[b * D + d] = m;
}

// ---------------- MLP head: 320->256 relu -> 16 relu -> 1 ----------------
__global__ __launch_bounds__(256) void k_mlp(const float* __restrict__ G,
    const float* __restrict__ Wf1, const float* __restrict__ bf1,
    const float* __restrict__ Wf2, const float* __restrict__ bf2,
    const float* __restrict__ Wf3, const float* __restrict__ bf3,
    float* __restrict__ out) {
    __shared__ float g_s[D];
    __shared__ float s1[256];
    __shared__ float s2[16];
    int b = blockIdx.x;
    int t = threadIdx.x;
    for (int i = t; i < D; i += 256) g_s[i] = G[b * D + i];
    __syncthreads();
    float acc = bf1[t];
    for (int k = 0; k < D; ++k) acc = fmaf(g_s[k], Wf1[k * 256 + t], acc);
    s1[t] = fmaxf(acc, 0.0f);
    __syncthreads();
    if (t < 16) {
        float a2 = bf2[t];
        for (int k = 0; k < 256; ++k) a2 = fmaf(s1[k], Wf2[k * 16 + t], a2);
        s2[t] = fmaxf(a2, 0.0f);
    }
    __syncthreads();
    if (t == 0) {
        float a3 = bf3[0];
        #pragma unroll
        for (int k = 0; k < 16; ++k) a3 = fmaf(s2[k], Wf3[k], a3);
        out[b] = a3;
    }
}

extern "C" void kernel_launch(void* const* d_in, const int* in_sizes, int n_in,
                              void* d_out, int out_size, void* d_ws, size_t ws_size,
                              hipStream_t stream) {
    const float* x   = (const float*)d_in[0];
    const float* W1  = (const float*)d_in[1];
    const float* b1  = (const float*)d_in[2];
    const float* W2  = (const float*)d_in[3];
    const float* b2  = (const float*)d_in[4];
    const float* W3  = (const float*)d_in[5];
    const float* b3  = (const float*)d_in[6];
    const float* Wf1 = (const float*)d_in[7];
    const float* bf1 = (const float*)d_in[8];
    const float* Wf2 = (const float*)d_in[9];
    const float* bf2 = (const float*)d_in[10];
    const float* Wf3 = (const float*)d_in[11];
    const float* bf3 = (const float*)d_in[12];
    const int*   ei  = (const int*)d_in[13];
    const int*   src = ei;
    const int*   dst = ei + N_EDGES;
    const int*   batch = (const int*)d_in[14];
    float* out = (float*)d_out;

    // workspace layout (~132 MB)
    char* ws = (char*)d_ws;
    float* pA   = (float*)ws; ws += (size_t)N_NODES * D * 4;   // 64 MB
    float* pB   = (float*)ws; ws += (size_t)N_NODES * D * 4;   // 64 MB
    float* dinv = (float*)ws; ws += 200000;
    int*   degi = (int*)ws;   ws += 200000;
    int*   offs = (int*)ws;   ws += 200064;
    int*   cursor = (int*)ws; ws += 200000;
    int*   csr  = (int*)ws;   ws += (size_t)N_EDGES * 4;       // 3.2 MB
    float* G    = (float*)ws; ws += N_GRAPHS * D * 4;

    hipMemsetAsync(degi, 0, N_NODES * sizeof(int), stream);
    hipMemsetAsync(cursor, 0, N_NODES * sizeof(int), stream);

    k_deg<<<(N_EDGES + 255) / 256, 256, 0, stream>>>(dst, degi);
    k_dinv<<<(N_NODES + 255) / 256, 256, 0, stream>>>(degi, dinv);
    k_scan<<<1, 1024, 0, stream>>>(degi, offs);
    k_fill<<<(N_EDGES + 255) / 256, 256, 0, stream>>>(src, dst, offs, cursor, csr);

    dim3 ggrid((N_NODES + BM - 1) / BM, D / BN);
    // layer 1
    k_gemm<<<ggrid, 256, 0, stream>>>(x, W1, dinv, pA);
    k_agg<<<N_NODES, D, 0, stream>>>(pA, offs, csr, dinv, b1, pB);
    // layer 2
    k_gemm<<<ggrid, 256, 0, stream>>>(pB, W2, dinv, pA);
    k_agg<<<N_NODES, D, 0, stream>>>(pA, offs, csr, dinv, b2, pB);
    // layer 3
    k_gemm<<<ggrid, 256, 0, stream>>>(pB, W3, dinv, pA);
    k_agg<<<N_NODES, D, 0, stream>>>(pA, offs, csr, dinv, b3, pB);
    // pool + MLP
    k_pool<<<N_GRAPHS, D, 0, stream>>>(pB, batch, G);
    k_mlp<<<N_GRAPHS, 256, 0, stream>>>(G, Wf1, bf1, Wf2, bf2, Wf3, bf3, out);
}

// Round 2
// 680.084 us; speedup vs baseline: 2.1964x; 2.1964x over previous
//
#include <hip/hip_runtime.h>
#include <hip/hip_bf16.h>

#define N_NODES 50000
#define N_EDGES 800000
#define N_GRAPHS 64
#define D 320
#define SCAN_B 256
#define NBLK ((N_NODES + SCAN_B - 1) / SCAN_B)   // 196

typedef __attribute__((ext_vector_type(8))) short s16x8;
typedef __attribute__((ext_vector_type(4))) float f32x4;

__device__ inline ushort f2bf(float f) {
    __hip_bfloat16 h = __float2bfloat16(f);
    return *reinterpret_cast<ushort*>(&h);
}

// ---------------- conversions ----------------
__global__ __launch_bounds__(256) void k_cvt_x(const float* __restrict__ x,
                                               ushort* __restrict__ xb) {
    size_t i = ((size_t)blockIdx.x * blockDim.x + threadIdx.x) * 4;
    if (i >= (size_t)N_NODES * D) return;
    float4 v = *(const float4*)&x[i];
    ushort4 o;
    o.x = f2bf(v.x); o.y = f2bf(v.y); o.z = f2bf(v.z); o.w = f2bf(v.w);
    *(ushort4*)&xb[i] = o;
}

// W [k][n] f32 -> Wt [n][k] bf16
__global__ __launch_bounds__(256) void k_cvt_w(const float* __restrict__ W,
                                               ushort* __restrict__ Wt) {
    int i = blockIdx.x * blockDim.x + threadIdx.x;
    if (i >= D * D) return;
    int k = i / D, n = i % D;
    Wt[n * D + k] = f2bf(W[i]);
}

// ---------------- degree / dinv ----------------
__global__ void k_deg(const int* __restrict__ dst, int* __restrict__ degi) {
    int e = blockIdx.x * blockDim.x + threadIdx.x;
    if (e < N_EDGES) atomicAdd(&degi[dst[e]], 1);
}

__global__ void k_dinv(const int* __restrict__ degi, float* __restrict__ dinv) {
    int n = blockIdx.x * blockDim.x + threadIdx.x;
    if (n < N_NODES) dinv[n] = rsqrtf((float)(degi[n] + 1)); // +1 self loop
}

// ---------------- hierarchical exclusive scan ----------------
__global__ __launch_bounds__(SCAN_B) void k_scan1(const int* __restrict__ counts,
                                                  int* __restrict__ incl,
                                                  int* __restrict__ bsum) {
    __shared__ int tmp[SCAN_B];
    int t = threadIdx.x;
    int i = blockIdx.x * SCAN_B + t;
    int v = (i < N_NODES) ? counts[i] : 0;
    tmp[t] = v;
    __syncthreads();
    #pragma unroll
    for (int off = 1; off < SCAN_B; off <<= 1) {
        int xv = (t >= off) ? tmp[t - off] : 0;
        __syncthreads();
        tmp[t] += xv;
        __syncthreads();
    }
    if (i < N_NODES) incl[i] = tmp[t];
    if (t == SCAN_B - 1) bsum[blockIdx.x] = tmp[t];
}

__global__ __launch_bounds__(SCAN_B) void k_scan2(const int* __restrict__ bsum,
                                                  int* __restrict__ bex) {
    __shared__ int tmp[SCAN_B];
    int t = threadIdx.x;
    int v = (t < NBLK) ? bsum[t] : 0;
    tmp[t] = v;
    __syncthreads();
    #pragma unroll
    for (int off = 1; off < SCAN_B; off <<= 1) {
        int xv = (t >= off) ? tmp[t - off] : 0;
        __syncthreads();
        tmp[t] += xv;
        __syncthreads();
    }
    bex[t] = tmp[t] - v;  // exclusive
}

__global__ __launch_bounds__(SCAN_B) void k_scan3(const int* __restrict__ incl,
                                                  const int* __restrict__ bex,
                                                  int* __restrict__ offs) {
    int i = blockIdx.x * SCAN_B + threadIdx.x;
    if (i == 0) offs[0] = 0;
    if (i < N_NODES) offs[i + 1] = incl[i] + bex[i >> 8];
}

// ---------------- CSR fill (bucket by dst, store src) ----------------
__global__ void k_fill(const int* __restrict__ src, const int* __restrict__ dst,
                       const int* __restrict__ offs, int* __restrict__ cursor,
                       int* __restrict__ csr) {
    int e = blockIdx.x * blockDim.x + threadIdx.x;
    if (e < N_EDGES) {
        int d = dst[e];
        int p = atomicAdd(&cursor[d], 1);
        csr[offs[d] + p] = src[e];
    }
}

// ---------------- MFMA bf16 GEMM: P[m,n] = bf16(dinv[m] * sum_k A[m,k] Wt[n,k]) ----------------
#define GBM 128
#define GBN 64
#define GBK 32
#define LDK 40   // GBK + 8 shorts pad (80 B rows, 16B-aligned)
__global__ __launch_bounds__(256) void k_gemm(const ushort* __restrict__ A,
                                              const ushort* __restrict__ Wt,
                                              const float* __restrict__ dinv,
                                              ushort* __restrict__ P) {
    __shared__ ushort As[GBM][LDK];
    __shared__ ushort Bs[GBN][LDK];
    int t = threadIdx.x;
    int m0 = blockIdx.x * GBM;
    int n0 = blockIdx.y * GBN;
    int lane = t & 63;
    int wid = t >> 6;
    int wm = wid & 1;   // wave m-tile (64 rows)
    int wn = wid >> 1;  // wave n-tile (32 cols)
    int r16 = lane & 15;
    int kb = (lane >> 4) * 8;

    f32x4 acc[4][2] = {};

    int sr = t >> 2;   // 0..63
    int seg = t & 3;   // 16B segment within 32-k row

    for (int k0 = 0; k0 < D; k0 += GBK) {
        // stage A: 128 rows x 32 k (two 64-row halves)
        #pragma unroll
        for (int u = 0; u < 2; ++u) {
            int r = sr + 64 * u;
            int gr = m0 + r;
            s16x8 v = {};
            if (gr < N_NODES) v = *(const s16x8*)&A[(size_t)gr * D + k0 + seg * 8];
            *(s16x8*)&As[r][seg * 8] = v;
        }
        // stage B (Wt is [n][k]): 64 n-rows x 32 k
        *(s16x8*)&Bs[sr][seg * 8] = *(const s16x8*)&Wt[(size_t)(n0 + sr) * D + k0 + seg * 8];
        __syncthreads();

        s16x8 af[4], bf[2];
        #pragma unroll
        for (int mi = 0; mi < 4; ++mi)
            af[mi] = *(const s16x8*)&As[wm * 64 + mi * 16 + r16][kb];
        #pragma unroll
        for (int ni = 0; ni < 2; ++ni)
            bf[ni] = *(const s16x8*)&Bs[wn * 32 + ni * 16 + r16][kb];
        #pragma unroll
        for (int mi = 0; mi < 4; ++mi)
            #pragma unroll
            for (int ni = 0; ni < 2; ++ni)
                acc[mi][ni] = __builtin_amdgcn_mfma_f32_16x16x32_bf16(af[mi], bf[ni], acc[mi][ni], 0, 0, 0);
        __syncthreads();
    }

    // epilogue: C/D layout col=lane&15, row=(lane>>4)*4+reg
    #pragma unroll
    for (int mi = 0; mi < 4; ++mi) {
        int rbase = m0 + wm * 64 + mi * 16 + (lane >> 4) * 4;
        #pragma unroll
        for (int r = 0; r < 4; ++r) {
            int row = rbase + r;
            if (row < N_NODES) {
                float dv = dinv[row];
                #pragma unroll
                for (int ni = 0; ni < 2; ++ni) {
                    int col = n0 + wn * 32 + ni * 16 + r16;
                    P[(size_t)row * D + col] = f2bf(acc[mi][ni][r] * dv);
                }
            }
        }
    }
}

// ---------------- aggregation: H[n] = bf16(relu(dinv[n]*(P[n] + sum_{src->n} P[src]) + b)) ----------------
__global__ __launch_bounds__(320) void k_agg(const __hip_bfloat16* __restrict__ P,
                                             const int* __restrict__ offs,
                                             const int* __restrict__ csr,
                                             const float* __restrict__ dinv,
                                             const float* __restrict__ bias,
                                             __hip_bfloat16* __restrict__ H) {
    int n = blockIdx.x;
    int d = threadIdx.x;  // 320
    size_t nd = (size_t)n * D + d;
    float acc = __bfloat162float(P[nd]);  // self loop
    int i0 = offs[n], i1 = offs[n + 1];
    int i = i0;
    for (; i + 4 <= i1; i += 4) {
        int s0 = csr[i], s1 = csr[i + 1], s2 = csr[i + 2], s3 = csr[i + 3];
        float v0 = __bfloat162float(P[(size_t)s0 * D + d]);
        float v1 = __bfloat162float(P[(size_t)s1 * D + d]);
        float v2 = __bfloat162float(P[(size_t)s2 * D + d]);
        float v3 = __bfloat162float(P[(size_t)s3 * D + d]);
        acc += v0 + v1 + v2 + v3;
    }
    for (; i < i1; ++i) acc += __bfloat162float(P[(size_t)csr[i] * D + d]);
    H[nd] = __float2bfloat16(fmaxf(fmaf(dinv[n], acc, bias[d]), 0.0f));
}

// ---------------- global max pool: grid (5 ch-chunks, 64 graphs), block 256 ----------------
__global__ __launch_bounds__(256) void k_pool(const __hip_bfloat16* __restrict__ H,
                                              const int* __restrict__ batch,
                                              float* __restrict__ G) {
    __shared__ int range[2];
    __shared__ float red[4][64];
    int b = blockIdx.y;
    int c0 = blockIdx.x * 64;
    int t = threadIdx.x;
    int lane = t & 63, grp = t >> 6;
    if (t < 2) {
        int target = b + t;
        int lo = 0, hi = N_NODES;
        while (lo < hi) {
            int mid = (lo + hi) >> 1;
            if (batch[mid] < target) lo = mid + 1; else hi = mid;
        }
        range[t] = lo;
    }
    __syncthreads();
    int s = range[0], e = range[1];
    float m = -INFINITY;
    for (int n = s + grp; n < e; n += 4)
        m = fmaxf(m, __bfloat162float(H[(size_t)n * D + c0 + lane]));
    red[grp][lane] = m;
    __syncthreads();
    if (grp == 0) {
        m = fmaxf(fmaxf(red[0][lane], red[1][lane]), fmaxf(red[2][lane], red[3][lane]));
        G[b * D + c0 + lane] = m;
    }
}

// ---------------- MLP head: 320->256 relu -> 16 relu -> 1 ----------------
__global__ __launch_bounds__(256) void k_mlp(const float* __restrict__ G,
    const float* __restrict__ Wf1, const float* __restrict__ bf1,
    const float* __restrict__ Wf2, const float* __restrict__ bf2,
    const float* __restrict__ Wf3, const float* __restrict__ bf3,
    float* __restrict__ out) {
    __shared__ float g_s[D];
    __shared__ float s1[256];
    __shared__ float s2[16];
    int b = blockIdx.x;
    int t = threadIdx.x;
    for (int i = t; i < D; i += 256) g_s[i] = G[b * D + i];
    __syncthreads();
    float acc = bf1[t];
    for (int k = 0; k < D; ++k) acc = fmaf(g_s[k], Wf1[k * 256 + t], acc);
    s1[t] = fmaxf(acc, 0.0f);
    __syncthreads();
    if (t < 16) {
        float a2 = bf2[t];
        for (int k = 0; k < 256; ++k) a2 = fmaf(s1[k], Wf2[k * 16 + t], a2);
        s2[t] = fmaxf(a2, 0.0f);
    }
    __syncthreads();
    if (t == 0) {
        float a3 = bf3[0];
        #pragma unroll
        for (int k = 0; k < 16; ++k) a3 = fmaf(s2[k], Wf3[k], a3);
        out[b] = a3;
    }
}

extern "C" void kernel_launch(void* const* d_in, const int* in_sizes, int n_in,
                              void* d_out, int out_size, void* d_ws, size_t ws_size,
                              hipStream_t stream) {
    const float* x   = (const float*)d_in[0];
    const float* W1  = (const float*)d_in[1];
    const float* b1  = (const float*)d_in[2];
    const float* W2  = (const float*)d_in[3];
    const float* b2  = (const float*)d_in[4];
    const float* W3  = (const float*)d_in[5];
    const float* b3  = (const float*)d_in[6];
    const float* Wf1 = (const float*)d_in[7];
    const float* bf1 = (const float*)d_in[8];
    const float* Wf2 = (const float*)d_in[9];
    const float* bf2 = (const float*)d_in[10];
    const float* Wf3 = (const float*)d_in[11];
    const float* bf3 = (const float*)d_in[12];
    const int*   ei  = (const int*)d_in[13];
    const int*   src = ei;
    const int*   dst = ei + N_EDGES;
    const int*   batch = (const int*)d_in[14];
    float* out = (float*)d_out;

    // workspace layout (~101 MB)
    char* p = (char*)d_ws;
    auto alloc = [&](size_t bytes) { char* r = p; p += (bytes + 255) & ~(size_t)255; return (void*)r; };
    const size_t NB = (size_t)N_NODES * D * sizeof(ushort);  // 32 MB
    ushort* bA   = (ushort*)alloc(NB);
    ushort* bB   = (ushort*)alloc(NB);
    ushort* bC   = (ushort*)alloc(NB);
    ushort* Wt1  = (ushort*)alloc(D * D * 2);
    ushort* Wt2  = (ushort*)alloc(D * D * 2);
    ushort* Wt3  = (ushort*)alloc(D * D * 2);
    float*  dinv = (float*)alloc(N_NODES * 4);
    int*    degi = (int*)alloc(N_NODES * 4);
    int*    offs = (int*)alloc((N_NODES + 1) * 4);
    int*    cursor = (int*)alloc(N_NODES * 4);
    int*    csr  = (int*)alloc(N_EDGES * 4);
    int*    incl = (int*)alloc(N_NODES * 4);
    int*    bsum = (int*)alloc(SCAN_B * 4);
    int*    bex  = (int*)alloc(SCAN_B * 4);
    float*  G    = (float*)alloc(N_GRAPHS * D * 4);

    hipMemsetAsync(degi, 0, N_NODES * sizeof(int), stream);
    hipMemsetAsync(cursor, 0, N_NODES * sizeof(int), stream);

    // conversions
    k_cvt_x<<<(N_NODES * D / 4 + 255) / 256, 256, 0, stream>>>(x, bA);
    k_cvt_w<<<(D * D + 255) / 256, 256, 0, stream>>>(W1, Wt1);
    k_cvt_w<<<(D * D + 255) / 256, 256, 0, stream>>>(W2, Wt2);
    k_cvt_w<<<(D * D + 255) / 256, 256, 0, stream>>>(W3, Wt3);

    // graph prep
    k_deg<<<(N_EDGES + 255) / 256, 256, 0, stream>>>(dst, degi);
    k_dinv<<<(N_NODES + 255) / 256, 256, 0, stream>>>(degi, dinv);
    k_scan1<<<NBLK, SCAN_B, 0, stream>>>(degi, incl, bsum);
    k_scan2<<<1, SCAN_B, 0, stream>>>(bsum, bex);
    k_scan3<<<NBLK, SCAN_B, 0, stream>>>(incl, bex, offs);
    k_fill<<<(N_EDGES + 255) / 256, 256, 0, stream>>>(src, dst, offs, cursor, csr);

    dim3 ggrid((N_NODES + GBM - 1) / GBM, D / GBN);
    const __hip_bfloat16* bBh = (const __hip_bfloat16*)bB;
    // layer 1: bA -> bB -> bC
    k_gemm<<<ggrid, 256, 0, stream>>>(bA, Wt1, dinv, bB);
    k_agg<<<N_NODES, D, 0, stream>>>((const __hip_bfloat16*)bB, offs, csr, dinv, b1, (__hip_bfloat16*)bC);
    // layer 2: bC -> bB -> bA
    k_gemm<<<ggrid, 256, 0, stream>>>(bC, Wt2, dinv, bB);
    k_agg<<<N_NODES, D, 0, stream>>>((const __hip_bfloat16*)bB, offs, csr, dinv, b2, (__hip_bfloat16*)bA);
    // layer 3: bA -> bB -> bC
    k_gemm<<<ggrid, 256, 0, stream>>>(bA, Wt3, dinv, bB);
    k_agg<<<N_NODES, D, 0, stream>>>((const __hip_bfloat16*)bB, offs, csr, dinv, b3, (__hip_bfloat16*)bC);
    // pool + MLP
    dim3 pgrid(D / 64, N_GRAPHS);
    k_pool<<<pgrid, 256, 0, stream>>>((const __hip_bfloat16*)bC, batch, G);
    k_mlp<<<N_GRAPHS, 256, 0, stream>>>(G, Wf1, bf1, Wf2, bf2, Wf3, bf3, out);
}

// Round 3
// 521.113 us; speedup vs baseline: 2.8664x; 1.3051x over previous
//
#include <hip/hip_runtime.h>
#include <hip/hip_bf16.h>

#define N_NODES 50000
#define N_EDGES 800000
#define N_GRAPHS 64
#define D 320
#define SCAN_B 256
#define NBLK ((N_NODES + SCAN_B - 1) / SCAN_B)   // 196

typedef __attribute__((ext_vector_type(8))) short s16x8;
typedef __attribute__((ext_vector_type(4))) float f32x4;

__device__ inline ushort f2bf(float f) {
    __hip_bfloat16 h = __float2bfloat16(f);
    return *reinterpret_cast<ushort*>(&h);
}
__device__ inline float bf2f(ushort u) {
    unsigned int x = ((unsigned int)u) << 16;
    return __uint_as_float(x);
}

// W [k][n] f32 -> Wt [n][k] bf16
__global__ __launch_bounds__(256) void k_cvt_w(const float* __restrict__ W,
                                               ushort* __restrict__ Wt) {
    int i = blockIdx.x * blockDim.x + threadIdx.x;
    if (i >= D * D) return;
    int k = i / D, n = i % D;
    Wt[n * D + k] = f2bf(W[i]);
}

// ---------------- degree / dinv ----------------
__global__ void k_deg(const int* __restrict__ dst, int* __restrict__ degi) {
    int e = blockIdx.x * blockDim.x + threadIdx.x;
    if (e < N_EDGES) atomicAdd(&degi[dst[e]], 1);
}

__global__ void k_dinv(const int* __restrict__ degi, float* __restrict__ dinv) {
    int n = blockIdx.x * blockDim.x + threadIdx.x;
    if (n < N_NODES) dinv[n] = rsqrtf((float)(degi[n] + 1)); // +1 self loop
}

// ---------------- hierarchical exclusive scan ----------------
__global__ __launch_bounds__(SCAN_B) void k_scan1(const int* __restrict__ counts,
                                                  int* __restrict__ incl,
                                                  int* __restrict__ bsum) {
    __shared__ int tmp[SCAN_B];
    int t = threadIdx.x;
    int i = blockIdx.x * SCAN_B + t;
    int v = (i < N_NODES) ? counts[i] : 0;
    tmp[t] = v;
    __syncthreads();
    #pragma unroll
    for (int off = 1; off < SCAN_B; off <<= 1) {
        int xv = (t >= off) ? tmp[t - off] : 0;
        __syncthreads();
        tmp[t] += xv;
        __syncthreads();
    }
    if (i < N_NODES) incl[i] = tmp[t];
    if (t == SCAN_B - 1) bsum[blockIdx.x] = tmp[t];
}

__global__ __launch_bounds__(SCAN_B) void k_scan2(const int* __restrict__ bsum,
                                                  int* __restrict__ bex) {
    __shared__ int tmp[SCAN_B];
    int t = threadIdx.x;
    int v = (t < NBLK) ? bsum[t] : 0;
    tmp[t] = v;
    __syncthreads();
    #pragma unroll
    for (int off = 1; off < SCAN_B; off <<= 1) {
        int xv = (t >= off) ? tmp[t - off] : 0;
        __syncthreads();
        tmp[t] += xv;
        __syncthreads();
    }
    bex[t] = tmp[t] - v;  // exclusive
}

__global__ __launch_bounds__(SCAN_B) void k_scan3(const int* __restrict__ incl,
                                                  const int* __restrict__ bex,
                                                  int* __restrict__ offs) {
    int i = blockIdx.x * SCAN_B + threadIdx.x;
    if (i == 0) offs[0] = 0;
    if (i < N_NODES) offs[i + 1] = incl[i] + bex[i >> 8];
}

// ---------------- CSR fill (bucket by dst, store src) ----------------
__global__ void k_fill(const int* __restrict__ src, const int* __restrict__ dst,
                       const int* __restrict__ offs, int* __restrict__ cursor,
                       int* __restrict__ csr) {
    int e = blockIdx.x * blockDim.x + threadIdx.x;
    if (e < N_EDGES) {
        int d = dst[e];
        int p = atomicAdd(&cursor[d], 1);
        csr[offs[d] + p] = src[e];
    }
}

// ---------------- MFMA bf16 GEMM: P[m,n] = bf16(dinv[m] * sum_k A[m,k] Wt[n,k]) ----------------
#define GBM 128
#define GBN 64
#define GBK 32
#define LDK 40   // GBK + 8 shorts pad (80 B rows, 16B-aligned)
template<bool F32A>
__global__ __launch_bounds__(256) void k_gemm(const void* __restrict__ Ain,
                                              const ushort* __restrict__ Wt,
                                              const float* __restrict__ dinv,
                                              ushort* __restrict__ P) {
    __shared__ ushort As[GBM][LDK];
    __shared__ ushort Bs[GBN][LDK];
    int t = threadIdx.x;
    int m0 = blockIdx.x * GBM;
    int n0 = blockIdx.y * GBN;
    int lane = t & 63;
    int wid = t >> 6;
    int wm = wid & 1;   // wave m-tile (64 rows)
    int wn = wid >> 1;  // wave n-tile (32 cols)
    int r16 = lane & 15;
    int kb = (lane >> 4) * 8;

    f32x4 acc[4][2] = {};

    int sr = t >> 2;   // 0..63
    int seg = t & 3;   // 16B segment within 32-k row

    for (int k0 = 0; k0 < D; k0 += GBK) {
        // stage A: 128 rows x 32 k (two 64-row halves)
        #pragma unroll
        for (int u = 0; u < 2; ++u) {
            int r = sr + 64 * u;
            int gr = m0 + r;
            s16x8 v = {};
            if (gr < N_NODES) {
                if constexpr (F32A) {
                    const float* Af = (const float*)Ain;
                    float4 a0 = *(const float4*)&Af[(size_t)gr * D + k0 + seg * 8];
                    float4 a1 = *(const float4*)&Af[(size_t)gr * D + k0 + seg * 8 + 4];
                    v[0] = (short)f2bf(a0.x); v[1] = (short)f2bf(a0.y);
                    v[2] = (short)f2bf(a0.z); v[3] = (short)f2bf(a0.w);
                    v[4] = (short)f2bf(a1.x); v[5] = (short)f2bf(a1.y);
                    v[6] = (short)f2bf(a1.z); v[7] = (short)f2bf(a1.w);
                } else {
                    const ushort* Ab = (const ushort*)Ain;
                    v = *(const s16x8*)&Ab[(size_t)gr * D + k0 + seg * 8];
                }
            }
            *(s16x8*)&As[r][seg * 8] = v;
        }
        // stage B (Wt is [n][k]): 64 n-rows x 32 k
        *(s16x8*)&Bs[sr][seg * 8] = *(const s16x8*)&Wt[(size_t)(n0 + sr) * D + k0 + seg * 8];
        __syncthreads();

        s16x8 af[4], bfr[2];
        #pragma unroll
        for (int mi = 0; mi < 4; ++mi)
            af[mi] = *(const s16x8*)&As[wm * 64 + mi * 16 + r16][kb];
        #pragma unroll
        for (int ni = 0; ni < 2; ++ni)
            bfr[ni] = *(const s16x8*)&Bs[wn * 32 + ni * 16 + r16][kb];
        #pragma unroll
        for (int mi = 0; mi < 4; ++mi)
            #pragma unroll
            for (int ni = 0; ni < 2; ++ni)
                acc[mi][ni] = __builtin_amdgcn_mfma_f32_16x16x32_bf16(af[mi], bfr[ni], acc[mi][ni], 0, 0, 0);
        __syncthreads();
    }

    // epilogue: C/D layout col=lane&15, row=(lane>>4)*4+reg
    #pragma unroll
    for (int mi = 0; mi < 4; ++mi) {
        int rbase = m0 + wm * 64 + mi * 16 + (lane >> 4) * 4;
        #pragma unroll
        for (int r = 0; r < 4; ++r) {
            int row = rbase + r;
            if (row < N_NODES) {
                float dv = dinv[row];
                #pragma unroll
                for (int ni = 0; ni < 2; ++ni) {
                    int col = n0 + wn * 32 + ni * 16 + r16;
                    P[(size_t)row * D + col] = f2bf(acc[mi][ni][r] * dv);
                }
            }
        }
    }
}

// ---------------- aggregation: H[n] = bf16(relu(dinv[n]*(P[n] + sum_{src->n} P[src]) + b))
// 8 nodes per 320-thread block; 40 threads per node; 8 channels (16B) per thread.
#define AGG_NPB 8
#define AGG_TPN 40
__global__ __launch_bounds__(320) void k_agg(const ushort* __restrict__ P,
                                             const int* __restrict__ offs,
                                             const int* __restrict__ csr,
                                             const float* __restrict__ dinv,
                                             const float* __restrict__ bias,
                                             ushort* __restrict__ H) {
    int t = threadIdx.x;
    int nl = t / AGG_TPN;         // 0..7
    int cg = t % AGG_TPN;         // 0..39
    int n  = blockIdx.x * AGG_NPB + nl;   // 6250*8 == 50000, always valid
    int c0 = cg * 8;
    size_t rowP = (size_t)n * D + c0;

    float acc[8];
    {
        s16x8 v = *(const s16x8*)&P[rowP];   // self loop
        #pragma unroll
        for (int j = 0; j < 8; ++j) acc[j] = bf2f((ushort)v[j]);
    }
    int i0 = offs[n], i1 = offs[n + 1];
    int i = i0;
    for (; i + 4 <= i1; i += 4) {
        int s0 = csr[i], s1 = csr[i + 1], s2 = csr[i + 2], s3 = csr[i + 3];
        s16x8 v0 = *(const s16x8*)&P[(size_t)s0 * D + c0];
        s16x8 v1 = *(const s16x8*)&P[(size_t)s1 * D + c0];
        s16x8 v2 = *(const s16x8*)&P[(size_t)s2 * D + c0];
        s16x8 v3 = *(const s16x8*)&P[(size_t)s3 * D + c0];
        #pragma unroll
        for (int j = 0; j < 8; ++j)
            acc[j] += (bf2f((ushort)v0[j]) + bf2f((ushort)v1[j])) +
                      (bf2f((ushort)v2[j]) + bf2f((ushort)v3[j]));
    }
    for (; i < i1; ++i) {
        int s = csr[i];
        s16x8 v = *(const s16x8*)&P[(size_t)s * D + c0];
        #pragma unroll
        for (int j = 0; j < 8; ++j) acc[j] += bf2f((ushort)v[j]);
    }
    float dv = dinv[n];
    s16x8 ov;
    #pragma unroll
    for (int j = 0; j < 8; ++j)
        ov[j] = (short)f2bf(fmaxf(fmaf(dv, acc[j], bias[c0 + j]), 0.0f));
    *(s16x8*)&H[rowP] = ov;
}

// ---------------- global max pool: one block per graph, 8-way node-parallel ----------------
__global__ __launch_bounds__(320) void k_pool(const ushort* __restrict__ H,
                                              const int* __restrict__ batch,
                                              float* __restrict__ G) {
    __shared__ int range[2];
    __shared__ float red[AGG_NPB][D];
    int b = blockIdx.x;
    int t = threadIdx.x;
    int nl = t / AGG_TPN;   // 0..7
    int cg = t % AGG_TPN;   // 0..39
    int c0 = cg * 8;
    if (t < 2) {
        int target = b + t;
        int lo = 0, hi = N_NODES;
        while (lo < hi) {
            int mid = (lo + hi) >> 1;
            if (batch[mid] < target) lo = mid + 1; else hi = mid;
        }
        range[t] = lo;
    }
    __syncthreads();
    int s = range[0], e = range[1];
    float m[8];
    #pragma unroll
    for (int j = 0; j < 8; ++j) m[j] = -INFINITY;
    for (int n = s + nl; n < e; n += AGG_NPB) {
        s16x8 v = *(const s16x8*)&H[(size_t)n * D + c0];
        #pragma unroll
        for (int j = 0; j < 8; ++j) m[j] = fmaxf(m[j], bf2f((ushort)v[j]));
    }
    #pragma unroll
    for (int j = 0; j < 8; ++j) red[nl][c0 + j] = m[j];
    __syncthreads();
    if (nl == 0) {
        #pragma unroll
        for (int j = 0; j < 8; ++j) {
            float mm = red[0][c0 + j];
            #pragma unroll
            for (int r = 1; r < AGG_NPB; ++r) mm = fmaxf(mm, red[r][c0 + j]);
            G[b * D + c0 + j] = mm;
        }
    }
}

// ---------------- MLP head: 320->256 relu -> 16 relu -> 1 ----------------
__global__ __launch_bounds__(256) void k_mlp(const float* __restrict__ G,
    const float* __restrict__ Wf1, const float* __restrict__ bf1,
    const float* __restrict__ Wf2, const float* __restrict__ bf2,
    const float* __restrict__ Wf3, const float* __restrict__ bf3,
    float* __restrict__ out) {
    __shared__ float g_s[D];
    __shared__ float s1[256];
    __shared__ float s2[16];
    int b = blockIdx.x;
    int t = threadIdx.x;
    for (int i = t; i < D; i += 256) g_s[i] = G[b * D + i];
    __syncthreads();
    float acc = bf1[t];
    for (int k = 0; k < D; ++k) acc = fmaf(g_s[k], Wf1[k * 256 + t], acc);
    s1[t] = fmaxf(acc, 0.0f);
    __syncthreads();
    if (t < 16) {
        float a2 = bf2[t];
        for (int k = 0; k < 256; ++k) a2 = fmaf(s1[k], Wf2[k * 16 + t], a2);
        s2[t] = fmaxf(a2, 0.0f);
    }
    __syncthreads();
    if (t == 0) {
        float a3 = bf3[0];
        #pragma unroll
        for (int k = 0; k < 16; ++k) a3 = fmaf(s2[k], Wf3[k], a3);
        out[b] = a3;
    }
}

extern "C" void kernel_launch(void* const* d_in, const int* in_sizes, int n_in,
                              void* d_out, int out_size, void* d_ws, size_t ws_size,
                              hipStream_t stream) {
    const float* x   = (const float*)d_in[0];
    const float* W1  = (const float*)d_in[1];
    const float* b1  = (const float*)d_in[2];
    const float* W2  = (const float*)d_in[3];
    const float* b2  = (const float*)d_in[4];
    const float* W3  = (const float*)d_in[5];
    const float* b3  = (const float*)d_in[6];
    const float* Wf1 = (const float*)d_in[7];
    const float* bf1 = (const float*)d_in[8];
    const float* Wf2 = (const float*)d_in[9];
    const float* bf2 = (const float*)d_in[10];
    const float* Wf3 = (const float*)d_in[11];
    const float* bf3 = (const float*)d_in[12];
    const int*   ei  = (const int*)d_in[13];
    const int*   src = ei;
    const int*   dst = ei + N_EDGES;
    const int*   batch = (const int*)d_in[14];
    float* out = (float*)d_out;

    // workspace layout (~69 MB)
    char* p = (char*)d_ws;
    auto alloc = [&](size_t bytes) { char* r = p; p += (bytes + 255) & ~(size_t)255; return (void*)r; };
    const size_t NB = (size_t)N_NODES * D * sizeof(ushort);  // 32 MB
    ushort* bB   = (ushort*)alloc(NB);
    ushort* bC   = (ushort*)alloc(NB);
    ushort* Wt1  = (ushort*)alloc(D * D * 2);
    ushort* Wt2  = (ushort*)alloc(D * D * 2);
    ushort* Wt3  = (ushort*)alloc(D * D * 2);
    float*  dinv = (float*)alloc(N_NODES * 4);
    int*    degi = (int*)alloc(N_NODES * 4);
    int*    offs = (int*)alloc((N_NODES + 1) * 4);
    int*    cursor = (int*)alloc(N_NODES * 4);
    int*    csr  = (int*)alloc(N_EDGES * 4);
    int*    incl = (int*)alloc(N_NODES * 4);
    int*    bsum = (int*)alloc(SCAN_B * 4);
    int*    bex  = (int*)alloc(SCAN_B * 4);
    float*  G    = (float*)alloc(N_GRAPHS * D * 4);

    hipMemsetAsync(degi, 0, N_NODES * sizeof(int), stream);
    hipMemsetAsync(cursor, 0, N_NODES * sizeof(int), stream);

    // weight conversions
    k_cvt_w<<<(D * D + 255) / 256, 256, 0, stream>>>(W1, Wt1);
    k_cvt_w<<<(D * D + 255) / 256, 256, 0, stream>>>(W2, Wt2);
    k_cvt_w<<<(D * D + 255) / 256, 256, 0, stream>>>(W3, Wt3);

    // graph prep
    k_deg<<<(N_EDGES + 255) / 256, 256, 0, stream>>>(dst, degi);
    k_dinv<<<(N_NODES + 255) / 256, 256, 0, stream>>>(degi, dinv);
    k_scan1<<<NBLK, SCAN_B, 0, stream>>>(degi, incl, bsum);
    k_scan2<<<1, SCAN_B, 0, stream>>>(bsum, bex);
    k_scan3<<<NBLK, SCAN_B, 0, stream>>>(incl, bex, offs);
    k_fill<<<(N_EDGES + 255) / 256, 256, 0, stream>>>(src, dst, offs, cursor, csr);

    dim3 ggrid((N_NODES + GBM - 1) / GBM, D / GBN);
    int agrid = N_NODES / AGG_NPB;  // 6250
    // layer 1: x(f32) -> bB -> bC
    k_gemm<true><<<ggrid, 256, 0, stream>>>(x, Wt1, dinv, bB);
    k_agg<<<agrid, 320, 0, stream>>>(bB, offs, csr, dinv, b1, bC);
    // layer 2: bC -> bB -> bC2 (reuse bB/bC ping-pong)
    k_gemm<false><<<ggrid, 256, 0, stream>>>(bC, Wt2, dinv, bB);
    k_agg<<<agrid, 320, 0, stream>>>(bB, offs, csr, dinv, b2, bC);
    // layer 3: bC -> bB -> bC
    k_gemm<false><<<ggrid, 256, 0, stream>>>(bC, Wt3, dinv, bB);
    k_agg<<<agrid, 320, 0, stream>>>(bB, offs, csr, dinv, b3, bC);
    // pool + MLP
    k_pool<<<N_GRAPHS, 320, 0, stream>>>(bC, batch, G);
    k_mlp<<<N_GRAPHS, 256, 0, stream>>>(G, Wf1, bf1, Wf2, bf2, Wf3, bf3, out);
}